// Round 6
// baseline (241.776 us; speedup 1.0000x reference)
//
#include <hip/hip_runtime.h>
#include <math.h>

#define NB 32
#define CC 1024
#define SS 784
#define SP 832           // padded S; columns [784,832) of sa are zeroed by pack kernel
#define DD 128
#define KK 64
#define OUTD 1024
#define KD 8192          // K*D
#define NSPLIT 13        // vlad s-splits (64 s each)
#define PSPLIT 32        // split-K for projection (8192 = 32*256)

// workspace layout (BYTE offsets)  -- total ~29.5 MB
#define OFF_XN    0                                   // bf16 (N,D,SP)
#define OFF_SA    (OFF_XN + NB*DD*SP*2)               // bf16 (N,K,SP)
#define OFF_WPK   (OFF_SA + NB*KK*SP*2)               // bf16 Wpool frag-packed (32*8*64*8)
#define OFF_WCK   (OFF_WPK + 32*8*64*8*2)             // bf16 Wconv frag-packed (16*64*8)
#define OFF_VLADP (OFF_WCK + 16*64*8*2)               // f32 (N,NSPLIT,KD) packed C-layout
#define OFF_SASUM (OFF_VLADP + NB*NSPLIT*KD*4)        // f32 (N,NSPLIT,K)
#define OFF_VLADN (OFF_SASUM + NB*NSPLIT*KK*4)        // f32 (N,KD)
#define OFF_OUTP  (OFF_VLADN + NB*KD*4)               // f32 (PSPLIT,N,OUT)

typedef __attribute__((ext_vector_type(8))) short bf16x8;   // 8 bf16 = 4 VGPRs
typedef __attribute__((ext_vector_type(4))) float f32x4;

__device__ __forceinline__ unsigned int pk_bf16(float a, float b) {
    unsigned int ua = __builtin_bit_cast(unsigned int, a);
    unsigned int ub = __builtin_bit_cast(unsigned int, b);
    ua += 0x7FFFu + ((ua >> 16) & 1u);
    ub += 0x7FFFu + ((ub >> 16) & 1u);
    return (ua >> 16) | (ub & 0xFFFF0000u);
}
__device__ __forceinline__ unsigned short f2bf(float a) {
    unsigned int ua = __builtin_bit_cast(unsigned int, a);
    ua += 0x7FFFu + ((ua >> 16) & 1u);
    return (unsigned short)(ua >> 16);
}
__device__ __forceinline__ float bf2f(unsigned short u) {
    unsigned int v = ((unsigned int)u) << 16;
    return __builtin_bit_cast(float, v);
}

// ---------------------------------------------------------------------------
// K1: pack Wpool/Wconv into MFMA A-fragment order + zero the sa pad columns.
// Wpk: [kt(32)][mt(8)][lane(64)][8]; Wck: [tile(16)][lane(64)][8]
// blocks 0..7: Wpool; block 8: Wconv; blocks 9..104: zero sa[:, :, 784:832).
// ---------------------------------------------------------------------------
__global__ __launch_bounds__(256)
void pack_weights(const float* __restrict__ Wpool, const float* __restrict__ Wconv,
                  unsigned short* __restrict__ Wpk, unsigned short* __restrict__ Wck,
                  unsigned short* __restrict__ sa)
{
    const int b = blockIdx.x;
    const int t = threadIdx.x;
    if (b < 8) {
#pragma unroll
        for (int i = 0; i < 8; i++) {
            const int id = t + 256 * i;            // 0..2047
            const int ktl = id >> 9;               // 0..3
            const int mt  = (id >> 6) & 7;
            const int l   = id & 63;
            const int lm = l & 15, quad = l >> 4;
            const int kt = b * 4 + ktl;
            const int d = mt * 16 + lm;
            const int c = kt * 32 + quad * 8;
            const float4 v0 = *(const float4*)&Wpool[(size_t)d * CC + c];
            const float4 v1 = *(const float4*)&Wpool[(size_t)d * CC + c + 4];
            unsigned int* dst = (unsigned int*)&Wpk[(size_t)((kt * 8 + mt) * 64 + l) * 8];
            dst[0] = pk_bf16(v0.x, v0.y); dst[1] = pk_bf16(v0.z, v0.w);
            dst[2] = pk_bf16(v1.x, v1.y); dst[3] = pk_bf16(v1.z, v1.w);
        }
    } else if (b == 8) {
#pragma unroll
        for (int i = 0; i < 4; i++) {
            const int id = t + 256 * i;            // 0..1023
            const int tile = id >> 6;
            const int l = id & 63;
            const int lm = l & 15, quad = l >> 4;
            const int k = (tile >> 2) * 16 + lm;
            const int d = (tile & 3) * 32 + quad * 8;
            const float4 v0 = *(const float4*)&Wconv[(size_t)k * DD + d];
            const float4 v1 = *(const float4*)&Wconv[(size_t)k * DD + d + 4];
            unsigned int* dst = (unsigned int*)&Wck[(size_t)(tile * 64 + l) * 8];
            dst[0] = pk_bf16(v0.x, v0.y); dst[1] = pk_bf16(v0.z, v0.w);
            dst[2] = pk_bf16(v1.x, v1.y); dst[3] = pk_bf16(v1.z, v1.w);
        }
    } else {
        // zero sa pad: 32 n x 64 k x 48 s bf16 = 24576 8B-chunks over 96 blocks
        const int id  = (b - 9) * 256 + t;         // 0..24575
        const int sgrp = id % 12;                  // 4-short group within 48 pad cols
        const int rem  = id / 12;
        const int k    = rem & 63;
        const int n    = rem >> 6;
        unsigned long long* p =
            (unsigned long long*)&sa[((size_t)(n * KK + k)) * SP + SS + sgrp * 4];
        *p = 0ull;
    }
}

// ---------------------------------------------------------------------------
// K2: pool GEMM + bias + L2-norm + assign GEMM + softmax.
// Block tile 128d x 16s, grid (49, N) = 1568 blocks (784 = 49*16, no s pad).
// PHASE 1: stage x[1024 c][16 s] -> LDS bf16 fragment order.  float4 loads
//   (64 c-rows/wave-instr, 16 B each; L2 absorbs granularity), 8-deep
//   batches with no intervening consumer -> 8 KB/wave in flight.
//   LDS transpose scatter uses XOR row swizzle  row = s ^ (oct&15)  which
//   spreads a wave's 64 u16 writes over all 32 banks (2-way = free).
// PHASE 2: K-loop: B-frag = swizzled 16B LDS read; A-frag = 16B global load
//   from L2-resident Wpk, prefetched.  No barriers.
// PHASE 3: bias + norm + assign MFMA + softmax.
// ---------------------------------------------------------------------------
__global__ __launch_bounds__(256, 4)
void pool_norm_assign(const float* __restrict__ x, const unsigned short* __restrict__ Wpk,
                      const float* __restrict__ bpool, const unsigned short* __restrict__ Wck,
                      const float* __restrict__ bconv,
                      unsigned short* __restrict__ xn, unsigned short* __restrict__ sa)
{
    const int n  = blockIdx.y;
    const int s0 = blockIdx.x * 16;
    const int t  = threadIdx.x;
    const int l  = t & 63;
    const int w  = t >> 6;       // wave 0..3
    const int lm = l & 15;
    const int quad = l >> 4;

    __shared__ alignas(16) unsigned short Bst[128 * 16 * 8];  // 32 KB, swizzled rows
    __shared__ alignas(16) unsigned short xnT[16 * 16 * 8];   // 4 KB [dblk][s][8]
    __shared__ float red[4][16];
    __shared__ float sums[4][16];

    // ---- PHASE 1: stage x slice (c innermost in lanes: 64 c/wave-instr)
    {
        const int cl = l;            // c-lane 0..63
        const int sq = w;            // wave = s-quad (4 s columns)
        const float* xb = x + (size_t)n * CC * SS + s0 + sq * 4;
#pragma unroll
        for (int h = 0; h < 2; h++) {
            float4 gv[8];
#pragma unroll
            for (int it = 0; it < 8; it++) {
                const int c = (h * 8 + it) * 64 + cl;
                gv[it] = *(const float4*)(xb + (size_t)c * SS);
            }
#pragma unroll
            for (int it = 0; it < 8; it++) {
                const int c = (h * 8 + it) * 64 + cl;
                const int oct = c >> 3, c7 = c & 7;
                const float* gf = (const float*)&gv[it];
#pragma unroll
                for (int j = 0; j < 4; j++) {
                    const int s = sq * 4 + j;
                    Bst[(size_t)(oct * 16 + (s ^ (oct & 15))) * 8 + c7] = f2bf(gf[j]);
                }
            }
        }
    }
    __syncthreads();

    // ---- PHASE 2: pool GEMM K-loop (no barriers, A prefetched)
    f32x4 acc[2];
    acc[0] = (f32x4){0.f, 0.f, 0.f, 0.f};
    acc[1] = (f32x4){0.f, 0.f, 0.f, 0.f};

    bf16x8 a_nxt[2];
#pragma unroll
    for (int i = 0; i < 2; i++)
        a_nxt[i] = *(const bf16x8*)&Wpk[(size_t)((w * 2 + i) * 64 + l) * 8];

    for (int kt = 0; kt < 32; kt++) {
        const bf16x8 a0 = a_nxt[0], a1 = a_nxt[1];
        if (kt < 31) {
#pragma unroll
            for (int i = 0; i < 2; i++)
                a_nxt[i] = *(const bf16x8*)&Wpk[(size_t)(((kt + 1) * 8 + w * 2 + i) * 64 + l) * 8];
        }
        const int oct = kt * 4 + quad;
        const bf16x8 bfrag = *(const bf16x8*)&Bst[(size_t)(oct * 16 + (lm ^ (oct & 15))) * 8];
        acc[0] = __builtin_amdgcn_mfma_f32_16x16x32_bf16(a0, bfrag, acc[0], 0, 0, 0);
        acc[1] = __builtin_amdgcn_mfma_f32_16x16x32_bf16(a1, bfrag, acc[1], 0, 0, 0);
    }

    // ---- PHASE 3a: bias + L2-norm over d.  C layout: d=(2w+i)*16+quad*4+r, s=lm
    float vals[2][4];
    float ssq = 0.f;
#pragma unroll
    for (int i = 0; i < 2; i++)
#pragma unroll
        for (int r = 0; r < 4; r++) {
            const int d = (w * 2 + i) * 16 + quad * 4 + r;
            const float v = acc[i][r] + bpool[d];
            vals[i][r] = v; ssq += v * v;
        }
    ssq += __shfl_xor(ssq, 16, 64);
    ssq += __shfl_xor(ssq, 32, 64);
    if (quad == 0) red[w][lm] = ssq;
    __syncthreads();
    const float scale = 1.f / fmaxf(sqrtf(red[0][lm] + red[1][lm] + red[2][lm] + red[3][lm]), 1e-12f);
    const int sg = s0 + lm;
    unsigned short* xnp = xn + (size_t)n * DD * SP;
#pragma unroll
    for (int i = 0; i < 2; i++)
#pragma unroll
        for (int r = 0; r < 4; r++) {
            const int d = (w * 2 + i) * 16 + quad * 4 + r;
            const float v = vals[i][r] * scale;
            xnp[(size_t)d * SP + sg] = f2bf(v);
            xnT[(size_t)(((d >> 3) * 16) + lm) * 8 + (d & 7)] = f2bf(v);
        }
    __syncthreads();

    // ---- PHASE 3b: assign GEMM (64k x 16s), wave w -> k-tile w
    f32x4 acc2 = (f32x4){0.f, 0.f, 0.f, 0.f};
#pragma unroll
    for (int dsv = 0; dsv < 4; dsv++) {
        const bf16x8 bfrag = *(const bf16x8*)&xnT[(size_t)((dsv * 4 + quad) * 16 + lm) * 8];
        const bf16x8 afrag = *(const bf16x8*)&Wck[(size_t)((w * 4 + dsv) * 64 + l) * 8];
        acc2 = __builtin_amdgcn_mfma_f32_16x16x32_bf16(afrag, bfrag, acc2, 0, 0, 0);
    }
    // softmax over k (|logits| <= ~1.5: unit-norm descriptors, no max-sub needed)
    float e[4]; float ps = 0.f;
#pragma unroll
    for (int r = 0; r < 4; r++) {
        const int k = w * 16 + quad * 4 + r;
        e[r] = expf(acc2[r] + bconv[k]);
        ps += e[r];
    }
    ps += __shfl_xor(ps, 16, 64);
    ps += __shfl_xor(ps, 32, 64);
    if (quad == 0) sums[w][lm] = ps;
    __syncthreads();
    const float inv = 1.f / (sums[0][lm] + sums[1][lm] + sums[2][lm] + sums[3][lm]);
    unsigned short* sap = sa + (size_t)n * KK * SP;
#pragma unroll
    for (int r = 0; r < 4; r++) {
        const int k = w * 16 + quad * 4 + r;
        sap[(size_t)k * SP + sg] = f2bf(e[r] * inv);
    }
}

// ---------------------------------------------------------------------------
// K3: vlad GEMM (MFMA, fragment loads direct from global, no LDS, no barrier).
// sasum computed in-register from the already-loaded sa fragments.
// C stored PACKED: vp[(kq*DD+d)*4 + r], k = kq*4+r -> 16B f32x4 stores.
// grid (NSPLIT, N) = 416 blocks; wave tile 32k x 64d.
// ---------------------------------------------------------------------------
__global__ __launch_bounds__(256)
void vlad_mfma(const unsigned short* __restrict__ xn, const unsigned short* __restrict__ sa,
               float* __restrict__ vladp, float* __restrict__ sasump)
{
    const int p = blockIdx.x;
    const int n = blockIdx.y;
    const int t = threadIdx.x;
    const int l = t & 63;
    const int w = t >> 6;
    const int kth = w & 1, nh = w >> 1;
    const int lm = l & 15, quad = l >> 4;

    const unsigned short* sap = sa + (size_t)n * KK * SP;
    const unsigned short* xnp = xn + (size_t)n * DD * SP;

    f32x4 acc[2][4];
#pragma unroll
    for (int j = 0; j < 2; j++)
#pragma unroll
        for (int i = 0; i < 4; i++) acc[j][i] = (f32x4){0.f, 0.f, 0.f, 0.f};
    float ksum[2] = {0.f, 0.f};

#pragma unroll
    for (int st = 0; st < 2; st++) {
        const int sb = p * 64 + st * 32 + quad * 8;
        bf16x8 af[2], bfv[4];
#pragma unroll
        for (int j = 0; j < 2; j++)
            af[j] = *(const bf16x8*)&sap[(size_t)((kth * 2 + j) * 16 + lm) * SP + sb];
#pragma unroll
        for (int i = 0; i < 4; i++)
            bfv[i] = *(const bf16x8*)&xnp[(size_t)((nh * 4 + i) * 16 + lm) * SP + sb];
#pragma unroll
        for (int j = 0; j < 2; j++)
#pragma unroll
            for (int i = 0; i < 4; i++)
                acc[j][i] = __builtin_amdgcn_mfma_f32_16x16x32_bf16(af[j], bfv[i], acc[j][i], 0, 0, 0);
#pragma unroll
        for (int j = 0; j < 2; j++)
#pragma unroll
            for (int e = 0; e < 8; e++)
                ksum[j] += bf2f((unsigned short)af[j][e]);
    }

    float* vp = vladp + ((size_t)n * NSPLIT + p) * KD;
#pragma unroll
    for (int j = 0; j < 2; j++)
#pragma unroll
        for (int i = 0; i < 4; i++) {
            const int kq = (kth * 2 + j) * 4 + quad;          // k = kq*4 + r
            const int d  = (nh * 4 + i) * 16 + lm;
            *(f32x4*)&vp[(size_t)(kq * DD + d) * 4] = acc[j][i];
        }

    // sasum: reduce over quads; waves nh==0 own the stores (nh==1 duplicates)
#pragma unroll
    for (int j = 0; j < 2; j++) {
        ksum[j] += __shfl_xor(ksum[j], 16, 64);
        ksum[j] += __shfl_xor(ksum[j], 32, 64);
    }
    if (nh == 0 && quad == 0) {
#pragma unroll
        for (int j = 0; j < 2; j++)
            sasump[((size_t)n * NSPLIT + p) * KK + (kth * 2 + j) * 16 + lm] = ksum[j];
    }
}

// ---------------------------------------------------------------------------
// K4: reduce NSPLIT partials (f32x4 reads), subtract centroids*sasum,
// L2-norm over k, write vladn.  grid (DD/16=8, N) = 256 blocks.
// ---------------------------------------------------------------------------
__global__ __launch_bounds__(256)
void vlad_finish(const float* __restrict__ vladp, const float* __restrict__ sasump,
                 const float* __restrict__ centroids, float* __restrict__ vladn)
{
    const int dg = blockIdx.x;
    const int n  = blockIdx.y;
    const int t  = threadIdx.x;
    const int kq = t & 15;
    const int d  = dg * 16 + (t >> 4);

    __shared__ float sas[KK];
    if (t < KK) {
        float sm = 0.f;
#pragma unroll
        for (int p = 0; p < NSPLIT; p++) sm += sasump[((size_t)n * NSPLIT + p) * KK + t];
        sas[t] = sm;
    }
    __syncthreads();

    f32x4 v = (f32x4){0.f, 0.f, 0.f, 0.f};
#pragma unroll
    for (int p = 0; p < NSPLIT; p++) {
        const f32x4 pr = *(const f32x4*)&vladp[((size_t)n * NSPLIT + p) * KD + (size_t)(kq * DD + d) * 4];
        v += pr;
    }
#pragma unroll
    for (int r = 0; r < 4; r++)
        v[r] -= centroids[(size_t)(kq * 4 + r) * DD + d] * sas[kq * 4 + r];

    float ssq = v[0] * v[0] + v[1] * v[1] + v[2] * v[2] + v[3] * v[3];
    ssq += __shfl_xor(ssq, 1, 64);
    ssq += __shfl_xor(ssq, 2, 64);
    ssq += __shfl_xor(ssq, 4, 64);
    ssq += __shfl_xor(ssq, 8, 64);
    const float scale = 1.f / fmaxf(sqrtf(ssq), 1e-12f);

    float* vo = vladn + (size_t)n * KD;
#pragma unroll
    for (int r = 0; r < 4; r++)
        vo[(size_t)(kq * 4 + r) * DD + d] = v[r] * scale;
}

// ---------------------------------------------------------------------------
// K5: projection via MFMA, barrier-free, no LDS.
// grid (OUT/64=16, PSPLIT=32) = 512 blocks; 8 K-steps of 32 c.
// ---------------------------------------------------------------------------
__global__ __launch_bounds__(256)
void proj_mfma(const float* __restrict__ vladn, const float* __restrict__ Wproj,
               float* __restrict__ outp)
{
    const int o0 = blockIdx.x * 64;
    const int c0 = blockIdx.y * (KD / PSPLIT);   // 256-wide c slice
    const int t  = threadIdx.x;
    const int l  = t & 63;
    const int w  = t >> 6;
    const int lm = l & 15, quad = l >> 4;
    const int o  = o0 + w * 16 + lm;

    f32x4 acc[2];
    acc[0] = (f32x4){0.f, 0.f, 0.f, 0.f};
    acc[1] = (f32x4){0.f, 0.f, 0.f, 0.f};

#pragma unroll 2
    for (int kt = 0; kt < 8; kt++) {
        const int c = c0 + kt * 32 + quad * 8;
        const float4 b0 = *(const float4*)&Wproj[(size_t)o * KD + c];
        const float4 b1 = *(const float4*)&Wproj[(size_t)o * KD + c + 4];
        float4 a00 = *(const float4*)&vladn[(size_t)(0 * 16 + lm) * KD + c];
        float4 a01 = *(const float4*)&vladn[(size_t)(0 * 16 + lm) * KD + c + 4];
        float4 a10 = *(const float4*)&vladn[(size_t)(16 + lm) * KD + c];
        float4 a11 = *(const float4*)&vladn[(size_t)(16 + lm) * KD + c + 4];
        union { unsigned int u[4]; bf16x8 v; } ub, ua0, ua1;
        ub.u[0] = pk_bf16(b0.x, b0.y); ub.u[1] = pk_bf16(b0.z, b0.w);
        ub.u[2] = pk_bf16(b1.x, b1.y); ub.u[3] = pk_bf16(b1.z, b1.w);
        ua0.u[0] = pk_bf16(a00.x, a00.y); ua0.u[1] = pk_bf16(a00.z, a00.w);
        ua0.u[2] = pk_bf16(a01.x, a01.y); ua0.u[3] = pk_bf16(a01.z, a01.w);
        ua1.u[0] = pk_bf16(a10.x, a10.y); ua1.u[1] = pk_bf16(a10.z, a10.w);
        ua1.u[2] = pk_bf16(a11.x, a11.y); ua1.u[3] = pk_bf16(a11.z, a11.w);
        acc[0] = __builtin_amdgcn_mfma_f32_16x16x32_bf16(ua0.v, ub.v, acc[0], 0, 0, 0);
        acc[1] = __builtin_amdgcn_mfma_f32_16x16x32_bf16(ua1.v, ub.v, acc[1], 0, 0, 0);
    }

#pragma unroll
    for (int a = 0; a < 2; a++)
#pragma unroll
        for (int r = 0; r < 4; r++) {
            const int nn = a * 16 + quad * 4 + r;
            outp[((size_t)blockIdx.y * NB + nn) * OUTD + o] = acc[a][r];
        }
}

// ---------------------------------------------------------------------------
// K6: sum projection partials + bproj, final L2 norm over OUT, write d_out.
// ---------------------------------------------------------------------------
__global__ __launch_bounds__(256)
void final_norm_kernel(const float* __restrict__ outp, const float* __restrict__ bproj,
                       float* __restrict__ out)
{
    const int n = blockIdx.x;
    const int t = threadIdx.x;
    const int o4 = t * 4;

    float4 a = *(const float4*)&bproj[o4];
#pragma unroll
    for (int p = 0; p < PSPLIT; p++) {
        const float4 pr = *(const float4*)&outp[((size_t)p * NB + n) * OUTD + o4];
        a.x += pr.x; a.y += pr.y; a.z += pr.z; a.w += pr.w;
    }
    float ssp = a.x * a.x + a.y * a.y + a.z * a.z + a.w * a.w;
#pragma unroll
    for (int off = 32; off > 0; off >>= 1) ssp += __shfl_down(ssp, off, 64);
    __shared__ float rs[4];
    if ((t & 63) == 0) rs[t >> 6] = ssp;
    __syncthreads();
    const float total = rs[0] + rs[1] + rs[2] + rs[3];
    const float scale = 1.f / fmaxf(sqrtf(total), 1e-12f);
    float4 o;
    o.x = a.x * scale; o.y = a.y * scale; o.z = a.z * scale; o.w = a.w * scale;
    *(float4*)&out[(size_t)n * OUTD + o4] = o;
}

// ---------------------------------------------------------------------------
extern "C" void kernel_launch(void* const* d_in, const int* in_sizes, int n_in,
                              void* d_out, int out_size, void* d_ws, size_t ws_size,
                              hipStream_t stream)
{
    const float* x         = (const float*)d_in[0];
    const float* Wpool     = (const float*)d_in[1];
    const float* bpool     = (const float*)d_in[2];
    const float* Wconv     = (const float*)d_in[3];
    const float* bconv     = (const float*)d_in[4];
    const float* centroids = (const float*)d_in[5];
    const float* Wproj     = (const float*)d_in[6];
    const float* bproj     = (const float*)d_in[7];
    float* out = (float*)d_out;
    char*  wsb = (char*)d_ws;

    unsigned short* xn     = (unsigned short*)(wsb + OFF_XN);
    unsigned short* sa     = (unsigned short*)(wsb + OFF_SA);
    unsigned short* Wpk    = (unsigned short*)(wsb + OFF_WPK);
    unsigned short* Wck    = (unsigned short*)(wsb + OFF_WCK);
    float*          vladp  = (float*)(wsb + OFF_VLADP);
    float*          sasump = (float*)(wsb + OFF_SASUM);
    float*          vladn  = (float*)(wsb + OFF_VLADN);
    float*          outp   = (float*)(wsb + OFF_OUTP);

    pack_weights<<<dim3(105), 256, 0, stream>>>(Wpool, Wconv, Wpk, Wck, sa);
    pool_norm_assign<<<dim3(SS / 16, NB), 256, 0, stream>>>(x, Wpk, bpool, Wck, bconv, xn, sa);
    vlad_mfma<<<dim3(NSPLIT, NB), 256, 0, stream>>>(xn, sa, vladp, sasump);
    vlad_finish<<<dim3(DD / 16, NB), 256, 0, stream>>>(vladp, sasump, centroids, vladn);
    proj_mfma<<<dim3(OUTD / 64, PSPLIT), 256, 0, stream>>>(vladn, Wproj, outp);
    final_norm_kernel<<<dim3(NB), 256, 0, stream>>>(outp, bproj, out);
}

// Round 7
// 237.835 us; speedup vs baseline: 1.0166x; 1.0166x over previous
//
#include <hip/hip_runtime.h>
#include <math.h>

#define NB 32
#define CC 1024
#define SS 784
#define SP 832           // padded S; columns [784,832) of sa are zeroed by pack kernel
#define DD 128
#define KK 64
#define OUTD 1024
#define KD 8192          // K*D
#define NSPLIT 13        // vlad s-splits (64 s each)
#define PSPLIT 32        // split-K for projection (8192 = 32*256)

// workspace layout (BYTE offsets)  -- total ~29.5 MB
#define OFF_XN    0                                   // bf16 (N,D,SP)
#define OFF_SA    (OFF_XN + NB*DD*SP*2)               // bf16 (N,K,SP)
#define OFF_WPK   (OFF_SA + NB*KK*SP*2)               // bf16 Wpool frag-packed (32*8*64*8)
#define OFF_WCK   (OFF_WPK + 32*8*64*8*2)             // bf16 Wconv frag-packed (16*64*8)
#define OFF_VLADP (OFF_WCK + 16*64*8*2)               // f32 (N,NSPLIT,KD) packed C-layout
#define OFF_SASUM (OFF_VLADP + NB*NSPLIT*KD*4)        // f32 (N,NSPLIT,K)
#define OFF_VLADN (OFF_SASUM + NB*NSPLIT*KK*4)        // f32 (N,KD)
#define OFF_OUTP  (OFF_VLADN + NB*KD*4)               // f32 (PSPLIT,N,OUT)

typedef __attribute__((ext_vector_type(8))) short bf16x8;   // 8 bf16 = 4 VGPRs
typedef __attribute__((ext_vector_type(4))) float f32x4;

__device__ __forceinline__ unsigned int pk_bf16(float a, float b) {
    unsigned int ua = __builtin_bit_cast(unsigned int, a);
    unsigned int ub = __builtin_bit_cast(unsigned int, b);
    ua += 0x7FFFu + ((ua >> 16) & 1u);
    ub += 0x7FFFu + ((ub >> 16) & 1u);
    return (ua >> 16) | (ub & 0xFFFF0000u);
}
__device__ __forceinline__ unsigned short f2bf(float a) {
    unsigned int ua = __builtin_bit_cast(unsigned int, a);
    ua += 0x7FFFu + ((ua >> 16) & 1u);
    return (unsigned short)(ua >> 16);
}
__device__ __forceinline__ float bf2f(unsigned short u) {
    unsigned int v = ((unsigned int)u) << 16;
    return __builtin_bit_cast(float, v);
}

// ---------------------------------------------------------------------------
// K1: pack Wpool/Wconv into MFMA A-fragment order + zero the sa pad columns.
// Wpk: [kt(32)][mt(8)][lane(64)][8]; Wck: [tile(16)][lane(64)][8]
// ---------------------------------------------------------------------------
__global__ __launch_bounds__(256)
void pack_weights(const float* __restrict__ Wpool, const float* __restrict__ Wconv,
                  unsigned short* __restrict__ Wpk, unsigned short* __restrict__ Wck,
                  unsigned short* __restrict__ sa)
{
    const int b = blockIdx.x;
    const int t = threadIdx.x;
    if (b < 8) {
#pragma unroll
        for (int i = 0; i < 8; i++) {
            const int id = t + 256 * i;            // 0..2047
            const int ktl = id >> 9;               // 0..3
            const int mt  = (id >> 6) & 7;
            const int l   = id & 63;
            const int lm = l & 15, quad = l >> 4;
            const int kt = b * 4 + ktl;
            const int d = mt * 16 + lm;
            const int c = kt * 32 + quad * 8;
            const float4 v0 = *(const float4*)&Wpool[(size_t)d * CC + c];
            const float4 v1 = *(const float4*)&Wpool[(size_t)d * CC + c + 4];
            unsigned int* dst = (unsigned int*)&Wpk[(size_t)((kt * 8 + mt) * 64 + l) * 8];
            dst[0] = pk_bf16(v0.x, v0.y); dst[1] = pk_bf16(v0.z, v0.w);
            dst[2] = pk_bf16(v1.x, v1.y); dst[3] = pk_bf16(v1.z, v1.w);
        }
    } else if (b == 8) {
#pragma unroll
        for (int i = 0; i < 4; i++) {
            const int id = t + 256 * i;            // 0..1023
            const int tile = id >> 6;
            const int l = id & 63;
            const int lm = l & 15, quad = l >> 4;
            const int k = (tile >> 2) * 16 + lm;
            const int d = (tile & 3) * 32 + quad * 8;
            const float4 v0 = *(const float4*)&Wconv[(size_t)k * DD + d];
            const float4 v1 = *(const float4*)&Wconv[(size_t)k * DD + d + 4];
            unsigned int* dst = (unsigned int*)&Wck[(size_t)(tile * 64 + l) * 8];
            dst[0] = pk_bf16(v0.x, v0.y); dst[1] = pk_bf16(v0.z, v0.w);
            dst[2] = pk_bf16(v1.x, v1.y); dst[3] = pk_bf16(v1.z, v1.w);
        }
    } else {
        // zero sa pad: 32 n x 64 k x 48 s bf16 -> 24576 8B-chunks over 96 blocks
        const int id  = (b - 9) * 256 + t;         // 0..24575
        const int sgrp = id % 12;
        const int rem  = id / 12;
        const int k    = rem & 63;
        const int n    = rem >> 6;
        unsigned long long* p =
            (unsigned long long*)&sa[((size_t)(n * KK + k)) * SP + SS + sgrp * 4];
        *p = 0ull;
    }
}

// ---------------------------------------------------------------------------
// K2: pool GEMM + bias + L2-norm + assign GEMM + softmax.
// Block tile 128d x 16s, grid (49, N) = 1568 blocks.
// PHASE 1: stage x[1024 c][16 s] -> LDS bf16 fragment order.
//   float2 loads, lane map (s-pair = l&7, c-row = l>>3): each wave-instr
//   touches 8 rows x 128 B CONTIGUOUS runs (DRAM-friendly), batched 16-deep
//   x2 with no consumer in between (deep queue).  LDS scatter uses the
//   verified XOR row swizzle (2-way aliasing = free).
// PHASE 2: K-loop: B-frag = swizzled 16B LDS read; A-frag = 16B global load
//   from L2-resident Wpk, prefetched.  No barriers.
// PHASE 3: bias + norm + assign MFMA + softmax.
// ---------------------------------------------------------------------------
__global__ __launch_bounds__(256, 4)
void pool_norm_assign(const float* __restrict__ x, const unsigned short* __restrict__ Wpk,
                      const float* __restrict__ bpool, const unsigned short* __restrict__ Wck,
                      const float* __restrict__ bconv,
                      unsigned short* __restrict__ xn, unsigned short* __restrict__ sa)
{
    const int n  = blockIdx.y;
    const int s0 = blockIdx.x * 16;
    const int t  = threadIdx.x;
    const int l  = t & 63;
    const int w  = t >> 6;       // wave 0..3
    const int lm = l & 15;
    const int quad = l >> 4;

    __shared__ alignas(16) unsigned short Bst[128 * 16 * 8];  // 32 KB, swizzled rows
    __shared__ alignas(16) unsigned short xnT[16 * 16 * 8];   // 4 KB [dblk][s][8]
    __shared__ float red[4][16];
    __shared__ float sums[4][16];

    // ---- PHASE 1: stage x slice
    {
        const int s_h = l & 7;           // s-pair index (s = 2*s_h, 2*s_h+1)
        const int cr  = l >> 3;          // c-row within 8-row group
        const int sl0 = 2 * s_h;
        const float* xb = x + (size_t)n * CC * SS + s0 + sl0;
        const int cw = w * 256 + cr;     // wave's c region base row

        float2 ga[16], gb[16];
#pragma unroll
        for (int it = 0; it < 16; it++)
            ga[it] = *(const float2*)(xb + (size_t)(cw + it * 8) * SS);
#pragma unroll
        for (int it = 0; it < 16; it++)
            gb[it] = *(const float2*)(xb + (size_t)(cw + 128 + it * 8) * SS);

#pragma unroll
        for (int it = 0; it < 16; it++) {
            const int oct = w * 32 + it;          // c7 = cr, swizzle = oct&15 = it&15
            const int sw = it & 15;
            Bst[(size_t)(oct * 16 + (sl0 ^ sw)) * 8 + cr]       = f2bf(ga[it].x);
            Bst[(size_t)(oct * 16 + ((sl0 + 1) ^ sw)) * 8 + cr] = f2bf(ga[it].y);
        }
#pragma unroll
        for (int it = 0; it < 16; it++) {
            const int oct = w * 32 + 16 + it;
            const int sw = it & 15;
            Bst[(size_t)(oct * 16 + (sl0 ^ sw)) * 8 + cr]       = f2bf(gb[it].x);
            Bst[(size_t)(oct * 16 + ((sl0 + 1) ^ sw)) * 8 + cr] = f2bf(gb[it].y);
        }
    }
    __syncthreads();

    // ---- PHASE 2: pool GEMM K-loop (no barriers, A prefetched)
    f32x4 acc[2];
    acc[0] = (f32x4){0.f, 0.f, 0.f, 0.f};
    acc[1] = (f32x4){0.f, 0.f, 0.f, 0.f};

    bf16x8 a_nxt[2];
#pragma unroll
    for (int i = 0; i < 2; i++)
        a_nxt[i] = *(const bf16x8*)&Wpk[(size_t)((w * 2 + i) * 64 + l) * 8];

    for (int kt = 0; kt < 32; kt++) {
        const bf16x8 a0 = a_nxt[0], a1 = a_nxt[1];
        if (kt < 31) {
#pragma unroll
            for (int i = 0; i < 2; i++)
                a_nxt[i] = *(const bf16x8*)&Wpk[(size_t)(((kt + 1) * 8 + w * 2 + i) * 64 + l) * 8];
        }
        const int oct = kt * 4 + quad;
        const bf16x8 bfrag = *(const bf16x8*)&Bst[(size_t)(oct * 16 + (lm ^ (oct & 15))) * 8];
        acc[0] = __builtin_amdgcn_mfma_f32_16x16x32_bf16(a0, bfrag, acc[0], 0, 0, 0);
        acc[1] = __builtin_amdgcn_mfma_f32_16x16x32_bf16(a1, bfrag, acc[1], 0, 0, 0);
    }

    // ---- PHASE 3a: bias + L2-norm over d.  C layout: d=(2w+i)*16+quad*4+r, s=lm
    float vals[2][4];
    float ssq = 0.f;
#pragma unroll
    for (int i = 0; i < 2; i++)
#pragma unroll
        for (int r = 0; r < 4; r++) {
            const int d = (w * 2 + i) * 16 + quad * 4 + r;
            const float v = acc[i][r] + bpool[d];
            vals[i][r] = v; ssq += v * v;
        }
    ssq += __shfl_xor(ssq, 16, 64);
    ssq += __shfl_xor(ssq, 32, 64);
    if (quad == 0) red[w][lm] = ssq;
    __syncthreads();
    const float scale = 1.f / fmaxf(sqrtf(red[0][lm] + red[1][lm] + red[2][lm] + red[3][lm]), 1e-12f);
    const int sg = s0 + lm;
    unsigned short* xnp = xn + (size_t)n * DD * SP;
#pragma unroll
    for (int i = 0; i < 2; i++)
#pragma unroll
        for (int r = 0; r < 4; r++) {
            const int d = (w * 2 + i) * 16 + quad * 4 + r;
            const float v = vals[i][r] * scale;
            xnp[(size_t)d * SP + sg] = f2bf(v);
            xnT[(size_t)(((d >> 3) * 16) + lm) * 8 + (d & 7)] = f2bf(v);
        }
    __syncthreads();

    // ---- PHASE 3b: assign GEMM (64k x 16s), wave w -> k-tile w
    f32x4 acc2 = (f32x4){0.f, 0.f, 0.f, 0.f};
#pragma unroll
    for (int dsv = 0; dsv < 4; dsv++) {
        const bf16x8 bfrag = *(const bf16x8*)&xnT[(size_t)((dsv * 4 + quad) * 16 + lm) * 8];
        const bf16x8 afrag = *(const bf16x8*)&Wck[(size_t)((w * 4 + dsv) * 64 + l) * 8];
        acc2 = __builtin_amdgcn_mfma_f32_16x16x32_bf16(afrag, bfrag, acc2, 0, 0, 0);
    }
    // softmax over k (|logits| <= ~1.5: unit-norm descriptors, no max-sub needed)
    float e[4]; float ps = 0.f;
#pragma unroll
    for (int r = 0; r < 4; r++) {
        const int k = w * 16 + quad * 4 + r;
        e[r] = expf(acc2[r] + bconv[k]);
        ps += e[r];
    }
    ps += __shfl_xor(ps, 16, 64);
    ps += __shfl_xor(ps, 32, 64);
    if (quad == 0) sums[w][lm] = ps;
    __syncthreads();
    const float inv = 1.f / (sums[0][lm] + sums[1][lm] + sums[2][lm] + sums[3][lm]);
    unsigned short* sap = sa + (size_t)n * KK * SP;
#pragma unroll
    for (int r = 0; r < 4; r++) {
        const int k = w * 16 + quad * 4 + r;
        sap[(size_t)k * SP + sg] = f2bf(e[r] * inv);
    }
}

// ---------------------------------------------------------------------------
// K3: vlad GEMM (MFMA, direct-from-global fragments, no LDS, no barrier).
// d-split: grid (NSPLIT, N, 2) = 832 blocks; block = 64k x 64d, wave = k-tile.
// C stored PACKED: vp[(kq*DD+d)*4 + r], k = kq*4+r -> 16B f32x4 stores.
// ---------------------------------------------------------------------------
__global__ __launch_bounds__(256)
void vlad_mfma(const unsigned short* __restrict__ xn, const unsigned short* __restrict__ sa,
               float* __restrict__ vladp, float* __restrict__ sasump)
{
    const int p = blockIdx.x;
    const int n = blockIdx.y;
    const int z = blockIdx.z;      // d-half
    const int t = threadIdx.x;
    const int l = t & 63;
    const int w = t >> 6;          // k-tile 0..3
    const int lm = l & 15, quad = l >> 4;

    const unsigned short* sap = sa + (size_t)n * KK * SP;
    const unsigned short* xnp = xn + (size_t)n * DD * SP;

    f32x4 acc[4];
#pragma unroll
    for (int i = 0; i < 4; i++) acc[i] = (f32x4){0.f, 0.f, 0.f, 0.f};
    float ksum = 0.f;

#pragma unroll
    for (int st = 0; st < 2; st++) {
        const int sb = p * 64 + st * 32 + quad * 8;
        const bf16x8 af = *(const bf16x8*)&sap[(size_t)(w * 16 + lm) * SP + sb];
        bf16x8 bfv[4];
#pragma unroll
        for (int i = 0; i < 4; i++)
            bfv[i] = *(const bf16x8*)&xnp[(size_t)((z * 4 + i) * 16 + lm) * SP + sb];
#pragma unroll
        for (int i = 0; i < 4; i++)
            acc[i] = __builtin_amdgcn_mfma_f32_16x16x32_bf16(af, bfv[i], acc[i], 0, 0, 0);
        if (z == 0) {
#pragma unroll
            for (int e = 0; e < 8; e++) ksum += bf2f((unsigned short)af[e]);
        }
    }

    float* vp = vladp + ((size_t)n * NSPLIT + p) * KD;
    const int kq = w * 4 + quad;                          // k = kq*4 + r
#pragma unroll
    for (int i = 0; i < 4; i++) {
        const int d = (z * 4 + i) * 16 + lm;
        *(f32x4*)&vp[(size_t)(kq * DD + d) * 4] = acc[i];
    }

    if (z == 0) {
        ksum += __shfl_xor(ksum, 16, 64);
        ksum += __shfl_xor(ksum, 32, 64);
        if (quad == 0)
            sasump[((size_t)n * NSPLIT + p) * KK + w * 16 + lm] = ksum;
    }
}

// ---------------------------------------------------------------------------
// K4: reduce NSPLIT partials (f32x4 reads), subtract centroids*sasum,
// L2-norm over k, write vladn.  grid (DD/16=8, N) = 256 blocks.
// ---------------------------------------------------------------------------
__global__ __launch_bounds__(256)
void vlad_finish(const float* __restrict__ vladp, const float* __restrict__ sasump,
                 const float* __restrict__ centroids, float* __restrict__ vladn)
{
    const int dg = blockIdx.x;
    const int n  = blockIdx.y;
    const int t  = threadIdx.x;
    const int kq = t & 15;
    const int d  = dg * 16 + (t >> 4);

    __shared__ float sas[KK];
    if (t < KK) {
        float sm = 0.f;
#pragma unroll
        for (int p = 0; p < NSPLIT; p++) sm += sasump[((size_t)n * NSPLIT + p) * KK + t];
        sas[t] = sm;
    }
    __syncthreads();

    f32x4 v = (f32x4){0.f, 0.f, 0.f, 0.f};
#pragma unroll
    for (int p = 0; p < NSPLIT; p++) {
        const f32x4 pr = *(const f32x4*)&vladp[((size_t)n * NSPLIT + p) * KD + (size_t)(kq * DD + d) * 4];
        v += pr;
    }
#pragma unroll
    for (int r = 0; r < 4; r++)
        v[r] -= centroids[(size_t)(kq * 4 + r) * DD + d] * sas[kq * 4 + r];

    float ssq = v[0] * v[0] + v[1] * v[1] + v[2] * v[2] + v[3] * v[3];
    ssq += __shfl_xor(ssq, 1, 64);
    ssq += __shfl_xor(ssq, 2, 64);
    ssq += __shfl_xor(ssq, 4, 64);
    ssq += __shfl_xor(ssq, 8, 64);
    const float scale = 1.f / fmaxf(sqrtf(ssq), 1e-12f);

    float* vo = vladn + (size_t)n * KD;
#pragma unroll
    for (int r = 0; r < 4; r++)
        vo[(size_t)(kq * 4 + r) * DD + d] = v[r] * scale;
}

// ---------------------------------------------------------------------------
// K5: projection via MFMA, barrier-free, no LDS.
// grid (OUT/64=16, PSPLIT=32) = 512 blocks; 8 K-steps of 32 c, unroll 4.
// ---------------------------------------------------------------------------
__global__ __launch_bounds__(256)
void proj_mfma(const float* __restrict__ vladn, const float* __restrict__ Wproj,
               float* __restrict__ outp)
{
    const int o0 = blockIdx.x * 64;
    const int c0 = blockIdx.y * (KD / PSPLIT);   // 256-wide c slice
    const int t  = threadIdx.x;
    const int l  = t & 63;
    const int w  = t >> 6;
    const int lm = l & 15, quad = l >> 4;
    const int o  = o0 + w * 16 + lm;

    f32x4 acc[2];
    acc[0] = (f32x4){0.f, 0.f, 0.f, 0.f};
    acc[1] = (f32x4){0.f, 0.f, 0.f, 0.f};

#pragma unroll 4
    for (int kt = 0; kt < 8; kt++) {
        const int c = c0 + kt * 32 + quad * 8;
        const float4 b0 = *(const float4*)&Wproj[(size_t)o * KD + c];
        const float4 b1 = *(const float4*)&Wproj[(size_t)o * KD + c + 4];
        float4 a00 = *(const float4*)&vladn[(size_t)(0 * 16 + lm) * KD + c];
        float4 a01 = *(const float4*)&vladn[(size_t)(0 * 16 + lm) * KD + c + 4];
        float4 a10 = *(const float4*)&vladn[(size_t)(16 + lm) * KD + c];
        float4 a11 = *(const float4*)&vladn[(size_t)(16 + lm) * KD + c + 4];
        union { unsigned int u[4]; bf16x8 v; } ub, ua0, ua1;
        ub.u[0] = pk_bf16(b0.x, b0.y); ub.u[1] = pk_bf16(b0.z, b0.w);
        ub.u[2] = pk_bf16(b1.x, b1.y); ub.u[3] = pk_bf16(b1.z, b1.w);
        ua0.u[0] = pk_bf16(a00.x, a00.y); ua0.u[1] = pk_bf16(a00.z, a00.w);
        ua0.u[2] = pk_bf16(a01.x, a01.y); ua0.u[3] = pk_bf16(a01.z, a01.w);
        ua1.u[0] = pk_bf16(a10.x, a10.y); ua1.u[1] = pk_bf16(a10.z, a10.w);
        ua1.u[2] = pk_bf16(a11.x, a11.y); ua1.u[3] = pk_bf16(a11.z, a11.w);
        acc[0] = __builtin_amdgcn_mfma_f32_16x16x32_bf16(ua0.v, ub.v, acc[0], 0, 0, 0);
        acc[1] = __builtin_amdgcn_mfma_f32_16x16x32_bf16(ua1.v, ub.v, acc[1], 0, 0, 0);
    }

#pragma unroll
    for (int a = 0; a < 2; a++)
#pragma unroll
        for (int r = 0; r < 4; r++) {
            const int nn = a * 16 + quad * 4 + r;
            outp[((size_t)blockIdx.y * NB + nn) * OUTD + o] = acc[a][r];
        }
}

// ---------------------------------------------------------------------------
// K6: sum projection partials + bproj, final L2 norm over OUT, write d_out.
// grid (N), block 1024 (16 waves): thread owns one o column; 32 independent
// coalesced partial loads -> deep queue, strong latency hiding.
// ---------------------------------------------------------------------------
__global__ __launch_bounds__(1024)
void final_norm_kernel(const float* __restrict__ outp, const float* __restrict__ bproj,
                       float* __restrict__ out)
{
    const int n = blockIdx.x;
    const int t = threadIdx.x;   // o

    float a = bproj[t];
#pragma unroll
    for (int p = 0; p < PSPLIT; p++)
        a += outp[((size_t)p * NB + n) * OUTD + t];

    float ssp = a * a;
#pragma unroll
    for (int off = 32; off > 0; off >>= 1) ssp += __shfl_down(ssp, off, 64);
    __shared__ float rs[16];
    if ((t & 63) == 0) rs[t >> 6] = ssp;
    __syncthreads();
    float total = 0.f;
#pragma unroll
    for (int g = 0; g < 16; g++) total += rs[g];
    const float scale = 1.f / fmaxf(sqrtf(total), 1e-12f);
    out[(size_t)n * OUTD + t] = a * scale;
}

// ---------------------------------------------------------------------------
extern "C" void kernel_launch(void* const* d_in, const int* in_sizes, int n_in,
                              void* d_out, int out_size, void* d_ws, size_t ws_size,
                              hipStream_t stream)
{
    const float* x         = (const float*)d_in[0];
    const float* Wpool     = (const float*)d_in[1];
    const float* bpool     = (const float*)d_in[2];
    const float* Wconv     = (const float*)d_in[3];
    const float* bconv     = (const float*)d_in[4];
    const float* centroids = (const float*)d_in[5];
    const float* Wproj     = (const float*)d_in[6];
    const float* bproj     = (const float*)d_in[7];
    float* out = (float*)d_out;
    char*  wsb = (char*)d_ws;

    unsigned short* xn     = (unsigned short*)(wsb + OFF_XN);
    unsigned short* sa     = (unsigned short*)(wsb + OFF_SA);
    unsigned short* Wpk    = (unsigned short*)(wsb + OFF_WPK);
    unsigned short* Wck    = (unsigned short*)(wsb + OFF_WCK);
    float*          vladp  = (float*)(wsb + OFF_VLADP);
    float*          sasump = (float*)(wsb + OFF_SASUM);
    float*          vladn  = (float*)(wsb + OFF_VLADN);
    float*          outp   = (float*)(wsb + OFF_OUTP);

    pack_weights<<<dim3(105), 256, 0, stream>>>(Wpool, Wconv, Wpk, Wck, sa);
    pool_norm_assign<<<dim3(SS / 16, NB), 256, 0, stream>>>(x, Wpk, bpool, Wck, bconv, xn, sa);
    vlad_mfma<<<dim3(NSPLIT, NB, 2), 256, 0, stream>>>(xn, sa, vladp, sasump);
    vlad_finish<<<dim3(DD / 16, NB), 256, 0, stream>>>(vladp, sasump, centroids, vladn);
    proj_mfma<<<dim3(OUTD / 64, PSPLIT), 256, 0, stream>>>(vladn, Wproj, outp);
    final_norm_kernel<<<dim3(NB), 1024, 0, stream>>>(outp, bproj, out);
}